// Round 10
// baseline (504.773 us; speedup 1.0000x reference)
//
#include <hip/hip_runtime.h>

#define N_N 100000
#define N_E 1600000
#define N_G 5000
#define HID 256
#define IND 14

#define NB 391        // buckets: dst>>8, 256 nodes each (391*256 = 100096)
#define CH 8192       // edges per binning block
#define NBLK 196      // ceil(N_E/CH)

typedef __bf16 bf16x8 __attribute__((ext_vector_type(8)));
typedef float f32x4 __attribute__((ext_vector_type(4)));
typedef unsigned short u16;
typedef unsigned int u32;

// ---- workspace layout (units of 4 bytes) ----
constexpr size_t OFF_OUTS  = 0;          // float[5120] (zeroed)
constexpr size_t ZERO_BYTES = 5120 * 4;
constexpr size_t OFF_GCNT  = 5120;       // float[5120] (fully written, no zero needed)
constexpr size_t OFF_ROWP  = 10240;      // int[100096]
constexpr size_t OFF_DEG   = 110336;     // int[100096]
constexpr size_t OFF_BCNT  = 210432;     // int[NBLK*NB]
constexpr size_t OFF_EBUF  = 287104;     // u32[N_E]
constexpr size_t OFF_CSRC  = 1887104;    // int[N_E]
constexpr size_t OFF_H1B   = 3487104;    // bf16[100096*256]
constexpr size_t OFF_WCAT  = 16299392;   // bf16[256*512]
constexpr size_t OFF_XP    = 16364928;   // bf16[N*16]
// end = 17164928 floats ~= 69 MB

__device__ __forceinline__ u32 f2b(float f) {
    u32 u = __float_as_uint(f);
    u32 r = u + 0x7FFFu + ((u >> 16) & 1u);
    return r >> 16;
}

#define ADD8(acc, v) do { \
    acc[0] += __uint_as_float(v.x << 16); \
    acc[1] += __uint_as_float(v.x & 0xFFFF0000u); \
    acc[2] += __uint_as_float(v.y << 16); \
    acc[3] += __uint_as_float(v.y & 0xFFFF0000u); \
    acc[4] += __uint_as_float(v.z << 16); \
    acc[5] += __uint_as_float(v.z & 0xFFFF0000u); \
    acc[6] += __uint_as_float(v.w << 16); \
    acc[7] += __uint_as_float(v.w & 0xFFFF0000u); \
} while (0)

// ---- merged: histograms + xpb pack + wcat + gcnt (binary search, no atomics) ----
#define PACK_N (N_N * 16)
#define PACK_BLKS (PACK_N / 256)         // 6250
#define WCAT_BLKS 512                    // 256*512/256
#define GCNT_BLKS 20
__global__ __launch_bounds__(256) void k_bcnt_prep(const int* __restrict__ ei,
                                                   const float* __restrict__ x, const float* __restrict__ pos,
                                                   const int* __restrict__ batch,
                                                   const float* __restrict__ W2l, const float* __restrict__ W2r,
                                                   int* __restrict__ bcnt, u16* __restrict__ xpb,
                                                   float* __restrict__ gcnt, u16* __restrict__ wcat) {
    __shared__ int hist[NB];
    int tid = threadIdx.x;
    int blk = blockIdx.x;
    if (blk < NBLK) {
        for (int i = tid; i < NB; i += 256) hist[i] = 0;
        __syncthreads();
        int base = blk * CH;
#pragma unroll
        for (int i = 0; i < 32; i++) {
            int e = base + i * 256 + tid;
            if (e < N_E) atomicAdd(&hist[ei[N_E + e] >> 8], 1);
        }
        __syncthreads();
        for (int i = tid; i < NB; i += 256) bcnt[(size_t)blk * NB + i] = hist[i];
    } else if (blk < NBLK + PACK_BLKS) {
        int idx = (blk - NBLK) * 256 + tid;
        int n = idx >> 4, f = idx & 15;
        float v = 0.f;
        if (f < 11) v = x[n * 11 + f];
        else if (f < 14) v = pos[n * 3 + (f - 11)];
        xpb[idx] = (u16)f2b(v);
    } else if (blk < NBLK + PACK_BLKS + WCAT_BLKS) {
        int i2 = (blk - NBLK - PACK_BLKS) * 256 + tid;
        int n = i2 >> 9, k = i2 & 511;
        float v = (k < 256) ? W2l[k * HID + n] : W2r[(k - 256) * HID + n];
        wcat[(size_t)n * 512 + k] = (u16)f2b(v);
    } else {
        int g = (blk - NBLK - PACK_BLKS - WCAT_BLKS) * 256 + tid;
        if (g < N_G) {
            int lo = 0, hi = N_N;
            while (lo < hi) { int mid = (lo + hi) >> 1; if (batch[mid] < g) lo = mid + 1; else hi = mid; }
            int lo2 = lo, hi2 = N_N;
            while (lo2 < hi2) { int mid = (lo2 + hi2) >> 1; if (batch[mid] < g + 1) lo2 = mid + 1; else hi2 = mid; }
            gcnt[g] = (float)(lo2 - lo);
        }
    }
}

// ---- bin edges into ebuf; all bases derived locally from bcnt (no scan kernel) ----
__global__ __launch_bounds__(512) void k_bfill(const int* __restrict__ ei, const int* __restrict__ bcnt,
                                               u32* __restrict__ ebuf) {
    __shared__ int cur[NB];
    __shared__ int sc[512];
    int t = threadIdx.x;
    int j = blockIdx.x;
    int pre = 0, tot = 0;
    if (t < NB) {
        for (int i = 0; i < NBLK; i++) {
            int v = bcnt[(size_t)i * NB + t];
            if (i < j) pre += v;
            tot += v;
        }
    }
    sc[t] = (t < NB) ? tot : 0;
    __syncthreads();
    for (int off = 1; off < 512; off <<= 1) {
        int u = (t >= off) ? sc[t - off] : 0;
        __syncthreads();
        sc[t] += u;
        __syncthreads();
    }
    if (t < NB) cur[t] = (sc[t] - tot) + pre;    // bucket base + within-column prefix
    __syncthreads();
    int base = j * CH;
#pragma unroll
    for (int i = 0; i < 16; i++) {
        int e = base + i * 512 + t;
        if (e < N_E) {
            int d = ei[N_E + e];
            int s = ei[e];
            int p = atomicAdd(&cur[d >> 8], 1);
            ebuf[p] = (u32)s | ((u32)(d & 255) << 17);
        }
    }
}

// ---- per-bucket counting sort -> csrc, deg, rowp (bases from bcnt column sums) ----
__global__ __launch_bounds__(256) void k_sort(const u32* __restrict__ ebuf, const int* __restrict__ bcnt,
                                              int* __restrict__ csrc, int* __restrict__ deg,
                                              int* __restrict__ rowp) {
    __shared__ int colsumL[NB + 1];
    __shared__ int red[256];
    __shared__ int degL[256];
    __shared__ int sc[256];
    __shared__ int curL[256];
    int t = threadIdx.x;
    int b = blockIdx.x;
    // column sums (thread t covers columns t and t+256)
    int s0 = 0, s1 = 0;
    for (int i = 0; i < NBLK; i++) {
        s0 += bcnt[(size_t)i * NB + t];
        if (t + 256 < NB) s1 += bcnt[(size_t)i * NB + t + 256];
    }
    if (t < NB) colsumL[t] = s0;
    if (t + 256 < NB) colsumL[t + 256] = s1;
    red[t] = ((t < b) ? s0 : 0) + ((t + 256 < b) ? s1 : 0);
    degL[t] = 0;
    __syncthreads();
    for (int off = 128; off > 0; off >>= 1) {
        if (t < off) red[t] += red[t + off];
        __syncthreads();
    }
    int bs = red[0];
    int be = bs + colsumL[b];
    for (int e = bs + t; e < be; e += 256)
        atomicAdd(&degL[ebuf[e] >> 17], 1);
    __syncthreads();
    int myDeg = degL[t];
    sc[t] = myDeg;
    __syncthreads();
    for (int off = 1; off < 256; off <<= 1) {
        int v = (t >= off) ? sc[t - off] : 0;
        __syncthreads();
        sc[t] += v;
        __syncthreads();
    }
    int excl = sc[t] - myDeg;
    int node = (b << 8) + t;       // always < 100096; deg=0 for node >= N_N
    deg[node] = myDeg;
    rowp[node] = bs + excl;
    curL[t] = bs + excl;
    __syncthreads();
    for (int e = bs + t; e < be; e += 256) {
        u32 w = ebuf[e];
        int p = atomicAdd(&curL[w >> 17], 1);
        csrc[p] = (int)(w & 0x1FFFFu);
    }
}

// ---- layer 1: wave-parallel CSR mean-agg on bf16 xp + dual matmul + relu -> bf16 ----
__global__ __launch_bounds__(256) void k_layer1(const u16* __restrict__ xpb,
                                                const int* __restrict__ rowp, const int* __restrict__ deg,
                                                const int* __restrict__ csrc,
                                                const float* __restrict__ W1l, const float* __restrict__ b1,
                                                const float* __restrict__ W1r, u16* __restrict__ h1b) {
    __shared__ float ms[16][16];
    __shared__ float hs[16][16];
    int tid = threadIdx.x;
    int wave = tid >> 6, lane = tid & 63;
    int eg = lane >> 1, c = lane & 1;
#pragma unroll
    for (int nn = 0; nn < 4; nn++) {
        int s = wave * 4 + nn;
        int node = blockIdx.x * 16 + s;
        int st = rowp[node], dg = deg[node];
        float a[8] = {};
        for (int e = st + eg; e < st + dg; e += 32) {
            int nb = csrc[e];
            uint4 v = *(const uint4*)(xpb + (size_t)nb * 16 + c * 8);
            ADD8(a, v);
        }
#pragma unroll
        for (int off = 32; off >= 2; off >>= 1) {
#pragma unroll
            for (int j = 0; j < 8; j++) a[j] += __shfl_down(a[j], off);
        }
        if (lane < 2) {
            float inv = 1.f / (float)max(dg, 1);
#pragma unroll
            for (int j = 0; j < 8; j++) ms[s][c * 8 + j] = a[j] * inv;
        } else if (lane < 4) {
            int cc = lane - 2;
            uint4 v = *(const uint4*)(xpb + (size_t)node * 16 + cc * 8);
            float h[8] = {};
            ADD8(h, v);
#pragma unroll
            for (int j = 0; j < 8; j++) hs[s][cc * 8 + j] = h[j];
        }
    }
    __syncthreads();
    int j = tid;
    float bj = b1[j];
    float acc[16];
#pragma unroll
    for (int ss = 0; ss < 16; ss++) acc[ss] = bj;
#pragma unroll
    for (int k = 0; k < IND; k++) {
        float wl = W1l[k * HID + j];
        float wr = W1r[k * HID + j];
#pragma unroll
        for (int ss = 0; ss < 16; ss++)
            acc[ss] = fmaf(ms[ss][k], wl, fmaf(hs[ss][k], wr, acc[ss]));
    }
    int base = blockIdx.x * 16;
#pragma unroll
    for (int ss = 0; ss < 16; ss++)
        h1b[(size_t)(base + ss) * HID + j] = (u16)f2b(fmaxf(acc[ss], 0.f));
}

// ---- FUSED agg + layer2: each block gathers/means its 64-row A-panel into LDS,
// then MFMA K-loop (mean||h1 vs wcat) + relu + Wout-dot + pool atomic.
// mean1 never materialized; gather (VMEM) and GEMM (MFMA) phases of co-resident
// blocks overlap on the CU (m114). ----
__global__ __launch_bounds__(256, 2) void k_aggl2(const u16* __restrict__ h1b, const int* __restrict__ rowp,
                                                  const int* __restrict__ deg, const int* __restrict__ csrc,
                                                  const u16* __restrict__ wcat, const float* __restrict__ b2,
                                                  const int* __restrict__ batch, const float* __restrict__ Wout,
                                                  float* __restrict__ outsum) {
    __shared__ u16 meanM[8][64][40];   // [k-chunk][row][32+8 pad]
    __shared__ u16 Bs[2][256][40];
    int tid = threadIdx.x;
    int wave = tid >> 6, lane = tid & 63;
    int quad = lane >> 4, m16 = lane & 15;
    int half = lane >> 5, l32 = lane & 31;
    int bm = blockIdx.x;
    // early prefetch of this lane's first h1 A-frag (kt=8) for the GEMM phase
    const size_t r0 = (size_t)(bm * 64 + wave * 16 + m16) * HID + quad * 8;
    uint4 aG = *(const uint4*)(h1b + r0);

    // ---- phase 1: gather-aggregate (half-wave per node, 8 rows in flight/wave) ----
    const size_t roff = (size_t)l32 * 8;
#pragma unroll 1
    for (int pr = 0; pr < 8; pr++) {
        int row = wave * 16 + pr * 2 + half;
        int node = bm * 64 + row;
        int st = 0, dg = 0;
        if (node < N_N) { st = rowp[node]; dg = deg[node]; }
        int end = st + dg;
        float accA[8] = {}, accB[8] = {};
        int e = st;
        for (; e + 4 <= end; e += 4) {
            int i0 = csrc[e], i1 = csrc[e + 1], i2 = csrc[e + 2], i3 = csrc[e + 3];
            uint4 v0 = *(const uint4*)(h1b + (size_t)i0 * HID + roff);
            uint4 v1 = *(const uint4*)(h1b + (size_t)i1 * HID + roff);
            uint4 v2 = *(const uint4*)(h1b + (size_t)i2 * HID + roff);
            uint4 v3 = *(const uint4*)(h1b + (size_t)i3 * HID + roff);
            ADD8(accA, v0); ADD8(accB, v1); ADD8(accA, v2); ADD8(accB, v3);
        }
        for (; e < end; e++) {
            int nb = csrc[e];
            uint4 v = *(const uint4*)(h1b + (size_t)nb * HID + roff);
            ADD8(accA, v);
        }
        float inv = 1.f / (float)max(dg, 1);
        uint4 o;
        o.x = f2b((accA[0] + accB[0]) * inv) | (f2b((accA[1] + accB[1]) * inv) << 16);
        o.y = f2b((accA[2] + accB[2]) * inv) | (f2b((accA[3] + accB[3]) * inv) << 16);
        o.z = f2b((accA[4] + accB[4]) * inv) | (f2b((accA[5] + accB[5]) * inv) << 16);
        o.w = f2b((accA[6] + accB[6]) * inv) | (f2b((accA[7] + accB[7]) * inv) << 16);
        *(uint4*)&meanM[l32 >> 2][row][(l32 & 3) * 8] = o;
    }
    __syncthreads();

    // ---- phase 2: GEMM. wave w computes C rows [w*16,+16) x all 256 cols ----
    f32x4 acc[16] = {};
    for (int kt2 = 0; kt2 < 8; kt2++) {
        __syncthreads();
#pragma unroll
        for (int h = 0; h < 2; h++) {
            int kt = kt2 * 2 + h;
#pragma unroll
            for (int i = 0; i < 4; i++) {
                int cidx = tid + 256 * i;
                int n = cidx >> 2, kc = cidx & 3;
                *(uint4*)&Bs[h][n][kc * 8] =
                    *(const uint4*)(wcat + (size_t)n * 512 + kt * 32 + kc * 8);
            }
        }
        __syncthreads();
#pragma unroll
        for (int h = 0; h < 2; h++) {
            int kt = kt2 * 2 + h;
            bf16x8 af;
            if (kt < 8) {
                af = *(const bf16x8*)&meanM[kt][wave * 16 + m16][quad * 8];
            } else {
                uint4 cur = aG;
                if (kt < 15) aG = *(const uint4*)(h1b + r0 + (size_t)(kt - 7) * 32);
                af = __builtin_bit_cast(bf16x8, cur);
            }
#pragma unroll
            for (int u = 0; u < 16; u++) {
                bf16x8 bf = *(const bf16x8*)&Bs[h][u * 16 + m16][quad * 8];
                acc[u] = __builtin_amdgcn_mfma_f32_16x16x32_bf16(af, bf, acc[u], 0, 0, 0);
            }
        }
    }
    // ---- epilogue: relu + Wout dot per row, reduce across 16 col-lanes, 1 atomic/row ----
    float wo[16], bb[16];
#pragma unroll
    for (int u = 0; u < 16; u++) { int col = u * 16 + m16; wo[u] = Wout[col]; bb[u] = b2[col]; }
#pragma unroll
    for (int i = 0; i < 4; i++) {
        float p = 0.f;
#pragma unroll
        for (int u = 0; u < 16; u++)
            p = fmaf(fmaxf(acc[u][i] + bb[u], 0.f), wo[u], p);
#pragma unroll
        for (int off = 8; off > 0; off >>= 1) p += __shfl_down(p, off, 16);
        int row = bm * 64 + wave * 16 + quad * 4 + i;
        if (m16 == 0 && row < N_N) atomicAdd(&outsum[batch[row]], p);
    }
}

// ---- output head ----
__global__ __launch_bounds__(256) void k_out(const float* __restrict__ outsum, const float* __restrict__ gcnt,
                                             const float* __restrict__ bout, float* __restrict__ out) {
    int g = blockIdx.x * 256 + threadIdx.x;
    if (g < N_G) out[g] = outsum[g] / fmaxf(gcnt[g], 1.f) + bout[0];
}

extern "C" void kernel_launch(void* const* d_in, const int* in_sizes, int n_in,
                              void* d_out, int out_size, void* d_ws, size_t ws_size,
                              hipStream_t stream) {
    const float* x    = (const float*)d_in[0];
    const float* pos  = (const float*)d_in[1];
    const int*   ei   = (const int*)d_in[2];
    const int*   batch= (const int*)d_in[3];
    const float* W1l  = (const float*)d_in[4];
    const float* b1   = (const float*)d_in[5];
    const float* W1r  = (const float*)d_in[6];
    const float* W2l  = (const float*)d_in[7];
    const float* b2   = (const float*)d_in[8];
    const float* W2r  = (const float*)d_in[9];
    const float* Wout = (const float*)d_in[10];
    const float* bout = (const float*)d_in[11];
    float* out = (float*)d_out;
    float* ws  = (float*)d_ws;

    float* outs  = ws + OFF_OUTS;
    float* gcnt  = ws + OFF_GCNT;
    int*   rowp  = (int*)(ws + OFF_ROWP);
    int*   deg   = (int*)(ws + OFF_DEG);
    int*   bcnt  = (int*)(ws + OFF_BCNT);
    u32*   ebuf  = (u32*)(ws + OFF_EBUF);
    int*   csrc  = (int*)(ws + OFF_CSRC);
    u16*   h1b   = (u16*)(ws + OFF_H1B);
    u16*   wcat  = (u16*)(ws + OFF_WCAT);
    u16*   xpb   = (u16*)(ws + OFF_XP);

    hipMemsetAsync(d_ws, 0, ZERO_BYTES, stream);
    k_bcnt_prep<<<NBLK + PACK_BLKS + WCAT_BLKS + GCNT_BLKS, 256, 0, stream>>>(
        ei, x, pos, batch, W2l, W2r, bcnt, xpb, gcnt, wcat);
    k_bfill <<<NBLK, 512, 0, stream>>>(ei, bcnt, ebuf);
    k_sort  <<<NB, 256, 0, stream>>>(ebuf, bcnt, csrc, deg, rowp);
    k_layer1<<<N_N / 16, 256, 0, stream>>>(xpb, rowp, deg, csrc, W1l, b1, W1r, h1b);
    k_aggl2 <<<(N_N + 63) / 64, 256, 0, stream>>>(h1b, rowp, deg, csrc, wcat, b2, batch, Wout, outs);
    k_out   <<<(N_G + 255) / 256, 256, 0, stream>>>(outs, gcnt, bout, out);
}

// Round 11
// 458.630 us; speedup vs baseline: 1.1006x; 1.1006x over previous
//
#include <hip/hip_runtime.h>

#define N_N 100000
#define N_E 1600000
#define N_G 5000
#define HID 256
#define IND 14

#define NB 391        // buckets: dst>>8, 256 nodes each (391*256 = 100096)
#define CH 8192       // edges per binning block
#define NBLK 196      // ceil(N_E/CH)

typedef __bf16 bf16x8 __attribute__((ext_vector_type(8)));
typedef float f32x4 __attribute__((ext_vector_type(4)));
typedef unsigned short u16;
typedef unsigned int u32;

// ---- workspace layout (units of 4 bytes) ----
constexpr size_t OFF_OUTS  = 0;          // float[5120] (zeroed)
constexpr size_t ZERO_BYTES = 5120 * 4;
constexpr size_t OFF_GCNT  = 5120;       // float[5120] (fully written)
constexpr size_t OFF_ROWP  = 10240;      // int[100096]
constexpr size_t OFF_DEG   = 110336;     // int[100096]
constexpr size_t OFF_BCNT  = 210432;     // int[NBLK*NB]
constexpr size_t OFF_EBUF  = 287104;     // u32[N_E]
constexpr size_t OFF_CSRC  = 1887104;    // int[N_E]
constexpr size_t OFF_H1B   = 3487104;    // bf16[100096*256]
constexpr size_t OFF_WCAT  = 16299392;   // bf16[256*512]
constexpr size_t OFF_XP    = 16364928;   // bf16[N*16]
constexpr size_t OFF_MEAN1B= 17164928;   // bf16[100096*256]
// end = 29977216 floats ~= 120 MB

__device__ __forceinline__ u32 f2b(float f) {
    u32 u = __float_as_uint(f);
    u32 r = u + 0x7FFFu + ((u >> 16) & 1u);
    return r >> 16;
}

#define ADD8(acc, v) do { \
    acc[0] += __uint_as_float(v.x << 16); \
    acc[1] += __uint_as_float(v.x & 0xFFFF0000u); \
    acc[2] += __uint_as_float(v.y << 16); \
    acc[3] += __uint_as_float(v.y & 0xFFFF0000u); \
    acc[4] += __uint_as_float(v.z << 16); \
    acc[5] += __uint_as_float(v.z & 0xFFFF0000u); \
    acc[6] += __uint_as_float(v.w << 16); \
    acc[7] += __uint_as_float(v.w & 0xFFFF0000u); \
} while (0)

// ---- merged: histograms + xpb pack + wcat + gcnt (binary search, no atomics) ----
#define PACK_N (N_N * 16)
#define PACK_BLKS (PACK_N / 256)         // 6250
#define WCAT_BLKS 512
#define GCNT_BLKS 20
__global__ __launch_bounds__(256) void k_bcnt_prep(const int* __restrict__ ei,
                                                   const float* __restrict__ x, const float* __restrict__ pos,
                                                   const int* __restrict__ batch,
                                                   const float* __restrict__ W2l, const float* __restrict__ W2r,
                                                   int* __restrict__ bcnt, u16* __restrict__ xpb,
                                                   float* __restrict__ gcnt, u16* __restrict__ wcat) {
    __shared__ int hist[NB];
    int tid = threadIdx.x;
    int blk = blockIdx.x;
    if (blk < NBLK) {
        for (int i = tid; i < NB; i += 256) hist[i] = 0;
        __syncthreads();
        int base = blk * CH;
#pragma unroll
        for (int i = 0; i < 32; i++) {
            int e = base + i * 256 + tid;
            if (e < N_E) atomicAdd(&hist[ei[N_E + e] >> 8], 1);
        }
        __syncthreads();
        for (int i = tid; i < NB; i += 256) bcnt[(size_t)blk * NB + i] = hist[i];
    } else if (blk < NBLK + PACK_BLKS) {
        int idx = (blk - NBLK) * 256 + tid;
        int n = idx >> 4, f = idx & 15;
        float v = 0.f;
        if (f < 11) v = x[n * 11 + f];
        else if (f < 14) v = pos[n * 3 + (f - 11)];
        xpb[idx] = (u16)f2b(v);
    } else if (blk < NBLK + PACK_BLKS + WCAT_BLKS) {
        int i2 = (blk - NBLK - PACK_BLKS) * 256 + tid;
        int n = i2 >> 9, k = i2 & 511;
        float v = (k < 256) ? W2l[k * HID + n] : W2r[(k - 256) * HID + n];
        wcat[(size_t)n * 512 + k] = (u16)f2b(v);
    } else {
        int g = (blk - NBLK - PACK_BLKS - WCAT_BLKS) * 256 + tid;
        if (g < N_G) {
            int lo = 0, hi = N_N;
            while (lo < hi) { int mid = (lo + hi) >> 1; if (batch[mid] < g) lo = mid + 1; else hi = mid; }
            int lo2 = lo, hi2 = N_N;
            while (lo2 < hi2) { int mid = (lo2 + hi2) >> 1; if (batch[mid] < g + 1) lo2 = mid + 1; else hi2 = mid; }
            gcnt[g] = (float)(lo2 - lo);
        }
    }
}

// ---- bin edges into ebuf; bases derived locally from bcnt (no scan kernel) ----
__global__ __launch_bounds__(512) void k_bfill(const int* __restrict__ ei, const int* __restrict__ bcnt,
                                               u32* __restrict__ ebuf) {
    __shared__ int cur[NB];
    __shared__ int sc[512];
    int t = threadIdx.x;
    int j = blockIdx.x;
    int pre = 0, tot = 0;
    if (t < NB) {
        for (int i = 0; i < NBLK; i++) {
            int v = bcnt[(size_t)i * NB + t];
            if (i < j) pre += v;
            tot += v;
        }
    }
    sc[t] = (t < NB) ? tot : 0;
    __syncthreads();
    for (int off = 1; off < 512; off <<= 1) {
        int u = (t >= off) ? sc[t - off] : 0;
        __syncthreads();
        sc[t] += u;
        __syncthreads();
    }
    if (t < NB) cur[t] = (sc[t] - tot) + pre;
    __syncthreads();
    int base = j * CH;
#pragma unroll
    for (int i = 0; i < 16; i++) {
        int e = base + i * 512 + t;
        if (e < N_E) {
            int d = ei[N_E + e];
            int s = ei[e];
            int p = atomicAdd(&cur[d >> 8], 1);
            ebuf[p] = (u32)s | ((u32)(d & 255) << 17);
        }
    }
}

// ---- per-bucket counting sort -> csrc, deg, rowp ----
__global__ __launch_bounds__(256) void k_sort(const u32* __restrict__ ebuf, const int* __restrict__ bcnt,
                                              int* __restrict__ csrc, int* __restrict__ deg,
                                              int* __restrict__ rowp) {
    __shared__ int colsumL[NB + 1];
    __shared__ int red[256];
    __shared__ int degL[256];
    __shared__ int sc[256];
    __shared__ int curL[256];
    int t = threadIdx.x;
    int b = blockIdx.x;
    int s0 = 0, s1 = 0;
    for (int i = 0; i < NBLK; i++) {
        s0 += bcnt[(size_t)i * NB + t];
        if (t + 256 < NB) s1 += bcnt[(size_t)i * NB + t + 256];
    }
    if (t < NB) colsumL[t] = s0;
    if (t + 256 < NB) colsumL[t + 256] = s1;
    red[t] = ((t < b) ? s0 : 0) + ((t + 256 < b) ? s1 : 0);
    degL[t] = 0;
    __syncthreads();
    for (int off = 128; off > 0; off >>= 1) {
        if (t < off) red[t] += red[t + off];
        __syncthreads();
    }
    int bs = red[0];
    int be = bs + colsumL[b];
    for (int e = bs + t; e < be; e += 256)
        atomicAdd(&degL[ebuf[e] >> 17], 1);
    __syncthreads();
    int myDeg = degL[t];
    sc[t] = myDeg;
    __syncthreads();
    for (int off = 1; off < 256; off <<= 1) {
        int v = (t >= off) ? sc[t - off] : 0;
        __syncthreads();
        sc[t] += v;
        __syncthreads();
    }
    int excl = sc[t] - myDeg;
    int node = (b << 8) + t;
    deg[node] = myDeg;
    rowp[node] = bs + excl;
    curL[t] = bs + excl;
    __syncthreads();
    for (int e = bs + t; e < be; e += 256) {
        u32 w = ebuf[e];
        int p = atomicAdd(&curL[w >> 17], 1);
        csrc[p] = (int)(w & 0x1FFFFu);
    }
}

// ---- layer 1: wave-parallel CSR mean-agg on bf16 xp + dual matmul + relu -> bf16 ----
__global__ __launch_bounds__(256) void k_layer1(const u16* __restrict__ xpb,
                                                const int* __restrict__ rowp, const int* __restrict__ deg,
                                                const int* __restrict__ csrc,
                                                const float* __restrict__ W1l, const float* __restrict__ b1,
                                                const float* __restrict__ W1r, u16* __restrict__ h1b) {
    __shared__ float ms[16][16];
    __shared__ float hs[16][16];
    int tid = threadIdx.x;
    int wave = tid >> 6, lane = tid & 63;
    int eg = lane >> 1, c = lane & 1;
#pragma unroll
    for (int nn = 0; nn < 4; nn++) {
        int s = wave * 4 + nn;
        int node = blockIdx.x * 16 + s;
        int st = rowp[node], dg = deg[node];
        float a[8] = {};
        for (int e = st + eg; e < st + dg; e += 32) {
            int nb = csrc[e];
            uint4 v = *(const uint4*)(xpb + (size_t)nb * 16 + c * 8);
            ADD8(a, v);
        }
#pragma unroll
        for (int off = 32; off >= 2; off >>= 1) {
#pragma unroll
            for (int j = 0; j < 8; j++) a[j] += __shfl_down(a[j], off);
        }
        if (lane < 2) {
            float inv = 1.f / (float)max(dg, 1);
#pragma unroll
            for (int j = 0; j < 8; j++) ms[s][c * 8 + j] = a[j] * inv;
        } else if (lane < 4) {
            int cc = lane - 2;
            uint4 v = *(const uint4*)(xpb + (size_t)node * 16 + cc * 8);
            float h[8] = {};
            ADD8(h, v);
#pragma unroll
            for (int j = 0; j < 8; j++) hs[s][cc * 8 + j] = h[j];
        }
    }
    __syncthreads();
    int j = tid;
    float bj = b1[j];
    float acc[16];
#pragma unroll
    for (int ss = 0; ss < 16; ss++) acc[ss] = bj;
#pragma unroll
    for (int k = 0; k < IND; k++) {
        float wl = W1l[k * HID + j];
        float wr = W1r[k * HID + j];
#pragma unroll
        for (int ss = 0; ss < 16; ss++)
            acc[ss] = fmaf(ms[ss][k], wl, fmaf(hs[ss][k], wr, acc[ss]));
    }
    int base = blockIdx.x * 16;
#pragma unroll
    for (int ss = 0; ss < 16; ss++)
        h1b[(size_t)(base + ss) * HID + j] = (u16)f2b(fmaxf(acc[ss], 0.f));
}

// ---- layer-2 mean aggregation: 1 wave/node, 4 rows in flight (R6 variant; pinned at
// the scattered-gather service-rate wall ~3.9 TB/s — R7/R10 falsified both more-ILP
// and fused-low-occupancy alternatives) ----
__global__ __launch_bounds__(256) void k_agg(const u16* __restrict__ h1b, const int* __restrict__ rowp,
                                             const int* __restrict__ deg, const int* __restrict__ csrc,
                                             u16* __restrict__ mean1b) {
    int tid = threadIdx.x;
    int node = blockIdx.x * 4 + (tid >> 6);
    int lane = tid & 63;
    int half = lane >> 5, l32 = lane & 31;
    int st = rowp[node], dg = deg[node];
    int end = st + dg;
    const size_t roff = (size_t)l32 * 8;
    float accA[8] = {}, accB[8] = {};
    int e = st + half;
    for (; e + 2 < end; e += 4) {
        int nb1 = csrc[e];
        int nb2 = csrc[e + 2];
        uint4 v1 = *(const uint4*)(h1b + (size_t)nb1 * HID + roff);
        uint4 v2 = *(const uint4*)(h1b + (size_t)nb2 * HID + roff);
        ADD8(accA, v1);
        ADD8(accB, v2);
    }
    if (e < end) {
        int nb = csrc[e];
        uint4 v = *(const uint4*)(h1b + (size_t)nb * HID + roff);
        ADD8(accA, v);
    }
    float acc[8];
#pragma unroll
    for (int j = 0; j < 8; j++) acc[j] = accA[j] + accB[j];
#pragma unroll
    for (int j = 0; j < 8; j++) acc[j] += __shfl_down(acc[j], 32);
    if (lane < 32) {
        float inv = 1.f / (float)max(dg, 1);
        uint4 o;
        o.x = f2b(acc[0] * inv) | (f2b(acc[1] * inv) << 16);
        o.y = f2b(acc[2] * inv) | (f2b(acc[3] * inv) << 16);
        o.z = f2b(acc[4] * inv) | (f2b(acc[5] * inv) << 16);
        o.w = f2b(acc[6] * inv) | (f2b(acc[7] * inv) << 16);
        *(uint4*)(mean1b + (size_t)node * HID + roff) = o;
    }
}

// ---- layer 2: bf16 MFMA GEMM, BM=64 (acc 64 VGPR, Bs 20 KB -> higher occupancy),
// direct-global A-frags + register prefetch; fused relu + Wout-dot + pool atomic ----
__global__ __launch_bounds__(256, 2) void k_layer2(const u16* __restrict__ mean1b, const u16* __restrict__ h1b,
                                                   const u16* __restrict__ wcat, const float* __restrict__ b2,
                                                   const int* __restrict__ batch, const float* __restrict__ Wout,
                                                   float* __restrict__ outsum) {
    __shared__ u16 Bs[256][40];
    int tid = threadIdx.x;
    int wave = tid >> 6, lane = tid & 63;
    int quad = lane >> 4, m16 = lane & 15;
    int bm = blockIdx.x;
    // this lane's A row; rows >= N_N read garbage inside buffer (rows exist up to 100096)
    // and are discarded by the epilogue guard
    const size_t r0 = (size_t)(bm * 64 + wave * 16 + m16) * HID + quad * 8;
    f32x4 acc[16] = {};
    uint4 a = *(const uint4*)(mean1b + r0);
    for (int kt = 0; kt < 16; kt++) {
        __syncthreads();
#pragma unroll
        for (int i = 0; i < 4; i++) {
            int cidx = tid + 256 * i;
            int n = cidx >> 2, kc = cidx & 3;
            *(uint4*)&Bs[n][kc * 8] = *(const uint4*)(wcat + (size_t)n * 512 + kt * 32 + kc * 8);
        }
        __syncthreads();
        uint4 cur = a;
        if (kt < 15) {
            int kg = (kt + 1) * 32;
            const u16* An = (kg < 256) ? (mean1b + kg) : (h1b + (kg - 256));
            a = *(const uint4*)(An + r0);
        }
        bf16x8 af = __builtin_bit_cast(bf16x8, cur);
#pragma unroll
        for (int u = 0; u < 16; u++) {
            bf16x8 bf = *(const bf16x8*)&Bs[u * 16 + m16][quad * 8];
            acc[u] = __builtin_amdgcn_mfma_f32_16x16x32_bf16(af, bf, acc[u], 0, 0, 0);
        }
    }
    float wo[16], bb[16];
#pragma unroll
    for (int u = 0; u < 16; u++) { int col = u * 16 + m16; wo[u] = Wout[col]; bb[u] = b2[col]; }
#pragma unroll
    for (int i = 0; i < 4; i++) {
        float p = 0.f;
#pragma unroll
        for (int u = 0; u < 16; u++)
            p = fmaf(fmaxf(acc[u][i] + bb[u], 0.f), wo[u], p);
#pragma unroll
        for (int off = 8; off > 0; off >>= 1) p += __shfl_down(p, off, 16);
        int row = bm * 64 + wave * 16 + quad * 4 + i;
        if (m16 == 0 && row < N_N) atomicAdd(&outsum[batch[row]], p);
    }
}

// ---- output head ----
__global__ __launch_bounds__(256) void k_out(const float* __restrict__ outsum, const float* __restrict__ gcnt,
                                             const float* __restrict__ bout, float* __restrict__ out) {
    int g = blockIdx.x * 256 + threadIdx.x;
    if (g < N_G) out[g] = outsum[g] / fmaxf(gcnt[g], 1.f) + bout[0];
}

extern "C" void kernel_launch(void* const* d_in, const int* in_sizes, int n_in,
                              void* d_out, int out_size, void* d_ws, size_t ws_size,
                              hipStream_t stream) {
    const float* x    = (const float*)d_in[0];
    const float* pos  = (const float*)d_in[1];
    const int*   ei   = (const int*)d_in[2];
    const int*   batch= (const int*)d_in[3];
    const float* W1l  = (const float*)d_in[4];
    const float* b1   = (const float*)d_in[5];
    const float* W1r  = (const float*)d_in[6];
    const float* W2l  = (const float*)d_in[7];
    const float* b2   = (const float*)d_in[8];
    const float* W2r  = (const float*)d_in[9];
    const float* Wout = (const float*)d_in[10];
    const float* bout = (const float*)d_in[11];
    float* out = (float*)d_out;
    float* ws  = (float*)d_ws;

    float* outs  = ws + OFF_OUTS;
    float* gcnt  = ws + OFF_GCNT;
    int*   rowp  = (int*)(ws + OFF_ROWP);
    int*   deg   = (int*)(ws + OFF_DEG);
    int*   bcnt  = (int*)(ws + OFF_BCNT);
    u32*   ebuf  = (u32*)(ws + OFF_EBUF);
    int*   csrc  = (int*)(ws + OFF_CSRC);
    u16*   h1b   = (u16*)(ws + OFF_H1B);
    u16*   wcat  = (u16*)(ws + OFF_WCAT);
    u16*   xpb   = (u16*)(ws + OFF_XP);
    u16*   mean1b= (u16*)(ws + OFF_MEAN1B);

    hipMemsetAsync(d_ws, 0, ZERO_BYTES, stream);
    k_bcnt_prep<<<NBLK + PACK_BLKS + WCAT_BLKS + GCNT_BLKS, 256, 0, stream>>>(
        ei, x, pos, batch, W2l, W2r, bcnt, xpb, gcnt, wcat);
    k_bfill <<<NBLK, 512, 0, stream>>>(ei, bcnt, ebuf);
    k_sort  <<<NB, 256, 0, stream>>>(ebuf, bcnt, csrc, deg, rowp);
    k_layer1<<<N_N / 16, 256, 0, stream>>>(xpb, rowp, deg, csrc, W1l, b1, W1r, h1b);
    k_agg   <<<N_N / 4, 256, 0, stream>>>(h1b, rowp, deg, csrc, mean1b);
    k_layer2<<<(N_N + 63) / 64, 256, 0, stream>>>(mean1b, h1b, wcat, b2, batch, Wout, outs);
    k_out   <<<(N_G + 255) / 256, 256, 0, stream>>>(outs, gcnt, bout, out);
}

// Round 13
// 417.415 us; speedup vs baseline: 1.2093x; 1.0987x over previous
//
#include <hip/hip_runtime.h>

#define N_N 100000
#define N_E 1600000
#define N_G 5000
#define HID 256
#define IND 14

#define NBUK 391      // buckets: dst>>8, 256 nodes each (391*256 = 100096)
#define CAP 5120      // static per-bucket capacity (E[cnt]=4096, sigma~64; +16 sigma)
#define CH2 2048      // edges per binning block
#define NFB 782       // ceil(N_E/CH2)

typedef __bf16 bf16x8 __attribute__((ext_vector_type(8)));
typedef float f32x4 __attribute__((ext_vector_type(4)));
typedef unsigned short u16;
typedef unsigned int u32;

// ---- workspace layout (units of 4 bytes) ----
// h1b/mean1b are bf16[100096*256] = 12,812,288 float-units EACH (R12 bug: this was
// halved, overlapping wcat/xp/mean1b into h1b -> garbage output)
constexpr size_t OFF_OUTS  = 0;          // float[5120]   (zeroed)
constexpr size_t OFF_GCUR  = 5120;       // int[391*16]   (zeroed, 64B-padded cursors)
constexpr size_t ZERO_END  = 11520;
constexpr size_t ZERO_BYTES = ZERO_END * 4;
constexpr size_t OFF_GCNT  = 11520;      // float[5120] (fully written)
constexpr size_t OFF_ROWP  = 16640;      // int[100096]
constexpr size_t OFF_DEG   = 116736;     // int[100096]
constexpr size_t OFF_EBUF  = 216832;     // u32[391*5120]
constexpr size_t OFF_CSRC  = 2218752;    // int[391*5120]
constexpr size_t OFF_H1B   = 4220672;    // bf16[100096*256] -> ends 17032960
constexpr size_t OFF_WCAT  = 17032960;   // bf16[256*512]    -> ends 17098496
constexpr size_t OFF_XP    = 17098496;   // bf16[N*16]       -> ends 17898496
constexpr size_t OFF_MEAN1B= 17898496;   // bf16[100096*256] -> ends 30710784
// end = 30710784 floats ~= 123 MB

__device__ __forceinline__ u32 f2b(float f) {
    u32 u = __float_as_uint(f);
    u32 r = u + 0x7FFFu + ((u >> 16) & 1u);
    return r >> 16;
}

#define ADD8(acc, v) do { \
    acc[0] += __uint_as_float(v.x << 16); \
    acc[1] += __uint_as_float(v.x & 0xFFFF0000u); \
    acc[2] += __uint_as_float(v.y << 16); \
    acc[3] += __uint_as_float(v.y & 0xFFFF0000u); \
    acc[4] += __uint_as_float(v.z << 16); \
    acc[5] += __uint_as_float(v.z & 0xFFFF0000u); \
    acc[6] += __uint_as_float(v.w << 16); \
    acc[7] += __uint_as_float(v.w & 0xFFFF0000u); \
} while (0)

// ---- prep: pack xp bf16 + wcat + gcnt (binary search) ----
#define PACK_N (N_N * 16)
#define PACK_BLKS (PACK_N / 256)         // 6250
#define WCAT_BLKS 512
#define GCNT_BLKS 20
__global__ __launch_bounds__(256) void k_prep(const float* __restrict__ x, const float* __restrict__ pos,
                                              const int* __restrict__ batch,
                                              const float* __restrict__ W2l, const float* __restrict__ W2r,
                                              u16* __restrict__ xpb, float* __restrict__ gcnt,
                                              u16* __restrict__ wcat) {
    int tid = threadIdx.x;
    int blk = blockIdx.x;
    if (blk < PACK_BLKS) {
        int idx = blk * 256 + tid;
        int n = idx >> 4, f = idx & 15;
        float v = 0.f;
        if (f < 11) v = x[n * 11 + f];
        else if (f < 14) v = pos[n * 3 + (f - 11)];
        xpb[idx] = (u16)f2b(v);
    } else if (blk < PACK_BLKS + WCAT_BLKS) {
        int i2 = (blk - PACK_BLKS) * 256 + tid;
        int n = i2 >> 9, k = i2 & 511;
        float v = (k < 256) ? W2l[k * HID + n] : W2r[(k - 256) * HID + n];
        wcat[(size_t)n * 512 + k] = (u16)f2b(v);
    } else {
        int g = (blk - PACK_BLKS - WCAT_BLKS) * 256 + tid;
        if (g < N_G) {
            int lo = 0, hi = N_N;
            while (lo < hi) { int mid = (lo + hi) >> 1; if (batch[mid] < g) lo = mid + 1; else hi = mid; }
            int lo2 = lo, hi2 = N_N;
            while (lo2 < hi2) { int mid = (lo2 + hi2) >> 1; if (batch[mid] < g + 1) lo2 = mid + 1; else hi2 = mid; }
            gcnt[g] = (float)(lo2 - lo);
        }
    }
}

// ---- single-phase binning: LDS histogram -> padded global-atomic range reservation
// in static per-bucket regions (base b*CAP) -> scatter. No bcnt matrix, no scans. ----
__global__ __launch_bounds__(256) void k_bfill(const int* __restrict__ ei, int* __restrict__ gcur,
                                               u32* __restrict__ ebuf) {
    __shared__ int hist[NBUK];
    __shared__ int curL[NBUK];
    int tid = threadIdx.x;
    int base = blockIdx.x * CH2;
    for (int i = tid; i < NBUK; i += 256) hist[i] = 0;
    __syncthreads();
#pragma unroll
    for (int i = 0; i < 8; i++) {
        int e = base + i * 256 + tid;
        if (e < N_E) atomicAdd(&hist[ei[N_E + e] >> 8], 1);
    }
    __syncthreads();
    for (int b = tid; b < NBUK; b += 256) {
        int c = hist[b];
        int o = c ? atomicAdd(&gcur[b * 16], c) : 0;
        curL[b] = b * CAP + o;
    }
    __syncthreads();
#pragma unroll
    for (int i = 0; i < 8; i++) {
        int e = base + i * 256 + tid;
        if (e < N_E) {
            int d = ei[N_E + e];
            int s = ei[e];
            int p = atomicAdd(&curL[d >> 8], 1);
            ebuf[p] = (u32)s | ((u32)(d & 255) << 17);
        }
    }
}

// ---- per-bucket counting sort -> csrc, deg, rowp (static bases, no prefix work) ----
__global__ __launch_bounds__(256) void k_sort(const u32* __restrict__ ebuf, const int* __restrict__ gcur,
                                              int* __restrict__ csrc, int* __restrict__ deg,
                                              int* __restrict__ rowp) {
    __shared__ int degL[256];
    __shared__ int sc[256];
    __shared__ int curL[256];
    int t = threadIdx.x;
    int b = blockIdx.x;
    int bs = b * CAP;
    int be = bs + gcur[b * 16];
    degL[t] = 0;
    __syncthreads();
    for (int e = bs + t; e < be; e += 256)
        atomicAdd(&degL[ebuf[e] >> 17], 1);
    __syncthreads();
    int myDeg = degL[t];
    sc[t] = myDeg;
    __syncthreads();
    for (int off = 1; off < 256; off <<= 1) {
        int v = (t >= off) ? sc[t - off] : 0;
        __syncthreads();
        sc[t] += v;
        __syncthreads();
    }
    int excl = sc[t] - myDeg;
    int node = (b << 8) + t;       // < 100096; deg=0 for node >= N_N
    deg[node] = myDeg;
    rowp[node] = bs + excl;
    curL[t] = bs + excl;
    __syncthreads();
    for (int e = bs + t; e < be; e += 256) {
        u32 w = ebuf[e];
        int p = atomicAdd(&curL[w >> 17], 1);
        csrc[p] = (int)(w & 0x1FFFFu);
    }
}

// ---- layer 1: wave-parallel CSR mean-agg on bf16 xp + dual matmul + relu -> bf16 ----
__global__ __launch_bounds__(256) void k_layer1(const u16* __restrict__ xpb,
                                                const int* __restrict__ rowp, const int* __restrict__ deg,
                                                const int* __restrict__ csrc,
                                                const float* __restrict__ W1l, const float* __restrict__ b1,
                                                const float* __restrict__ W1r, u16* __restrict__ h1b) {
    __shared__ float ms[16][16];
    __shared__ float hs[16][16];
    int tid = threadIdx.x;
    int wave = tid >> 6, lane = tid & 63;
    int eg = lane >> 1, c = lane & 1;
#pragma unroll
    for (int nn = 0; nn < 4; nn++) {
        int s = wave * 4 + nn;
        int node = blockIdx.x * 16 + s;
        int st = rowp[node], dg = deg[node];
        float a[8] = {};
        for (int e = st + eg; e < st + dg; e += 32) {
            int nb = csrc[e];
            uint4 v = *(const uint4*)(xpb + (size_t)nb * 16 + c * 8);
            ADD8(a, v);
        }
#pragma unroll
        for (int off = 32; off >= 2; off >>= 1) {
#pragma unroll
            for (int j = 0; j < 8; j++) a[j] += __shfl_down(a[j], off);
        }
        if (lane < 2) {
            float inv = 1.f / (float)max(dg, 1);
#pragma unroll
            for (int j = 0; j < 8; j++) ms[s][c * 8 + j] = a[j] * inv;
        } else if (lane < 4) {
            int cc = lane - 2;
            uint4 v = *(const uint4*)(xpb + (size_t)node * 16 + cc * 8);
            float h[8] = {};
            ADD8(h, v);
#pragma unroll
            for (int j = 0; j < 8; j++) hs[s][cc * 8 + j] = h[j];
        }
    }
    __syncthreads();
    int j = tid;
    float bj = b1[j];
    float acc[16];
#pragma unroll
    for (int ss = 0; ss < 16; ss++) acc[ss] = bj;
#pragma unroll
    for (int k = 0; k < IND; k++) {
        float wl = W1l[k * HID + j];
        float wr = W1r[k * HID + j];
#pragma unroll
        for (int ss = 0; ss < 16; ss++)
            acc[ss] = fmaf(ms[ss][k], wl, fmaf(hs[ss][k], wr, acc[ss]));
    }
    int base = blockIdx.x * 16;
#pragma unroll
    for (int ss = 0; ss < 16; ss++)
        h1b[(size_t)(base + ss) * HID + j] = (u16)f2b(fmaxf(acc[ss], 0.f));
}

// ---- layer-2 mean aggregation: 1 wave/node, 4 rows in flight (pinned at the
// scattered-gather service-rate wall ~3.9 TB/s; R7/R10 falsified alternatives) ----
__global__ __launch_bounds__(256) void k_agg(const u16* __restrict__ h1b, const int* __restrict__ rowp,
                                             const int* __restrict__ deg, const int* __restrict__ csrc,
                                             u16* __restrict__ mean1b) {
    int tid = threadIdx.x;
    int node = blockIdx.x * 4 + (tid >> 6);
    int lane = tid & 63;
    int half = lane >> 5, l32 = lane & 31;
    int st = rowp[node], dg = deg[node];
    int end = st + dg;
    const size_t roff = (size_t)l32 * 8;
    float accA[8] = {}, accB[8] = {};
    int e = st + half;
    for (; e + 2 < end; e += 4) {
        int nb1 = csrc[e];
        int nb2 = csrc[e + 2];
        uint4 v1 = *(const uint4*)(h1b + (size_t)nb1 * HID + roff);
        uint4 v2 = *(const uint4*)(h1b + (size_t)nb2 * HID + roff);
        ADD8(accA, v1);
        ADD8(accB, v2);
    }
    if (e < end) {
        int nb = csrc[e];
        uint4 v = *(const uint4*)(h1b + (size_t)nb * HID + roff);
        ADD8(accA, v);
    }
    float acc[8];
#pragma unroll
    for (int j = 0; j < 8; j++) acc[j] = accA[j] + accB[j];
#pragma unroll
    for (int j = 0; j < 8; j++) acc[j] += __shfl_down(acc[j], 32);
    if (lane < 32) {
        float inv = 1.f / (float)max(dg, 1);
        uint4 o;
        o.x = f2b(acc[0] * inv) | (f2b(acc[1] * inv) << 16);
        o.y = f2b(acc[2] * inv) | (f2b(acc[3] * inv) << 16);
        o.z = f2b(acc[4] * inv) | (f2b(acc[5] * inv) << 16);
        o.w = f2b(acc[6] * inv) | (f2b(acc[7] * inv) << 16);
        *(uint4*)(mean1b + (size_t)node * HID + roff) = o;
    }
}

// ---- layer 2 (R9 config: BM=128, Bs double-kt — measured ~24 us; BM=64 was 72 us):
// direct-global A-frags + register prefetch; fused relu + Wout-dot + pool atomic ----
__global__ __launch_bounds__(256, 2) void k_layer2(const u16* __restrict__ mean1b, const u16* __restrict__ h1b,
                                                   const u16* __restrict__ wcat, const float* __restrict__ b2,
                                                   const int* __restrict__ batch, const float* __restrict__ Wout,
                                                   float* __restrict__ outsum) {
    __shared__ u16 Bs[2][256][40];
    int tid = threadIdx.x;
    int wave = tid >> 6, lane = tid & 63;
    int quad = lane >> 4, m16 = lane & 15;
    int bm = blockIdx.x;
    const size_t r0 = (size_t)(bm * 128 + wave * 32 + m16) * HID + quad * 8;
    const size_t r1 = r0 + 16 * HID;
    f32x4 acc[2][16] = {};
    uint4 a0 = *(const uint4*)(mean1b + r0);
    uint4 a1 = *(const uint4*)(mean1b + r1);
    for (int kt2 = 0; kt2 < 8; kt2++) {
        __syncthreads();
#pragma unroll
        for (int h = 0; h < 2; h++) {
            int kt = kt2 * 2 + h;
#pragma unroll
            for (int i = 0; i < 4; i++) {
                int cidx = tid + 256 * i;
                int n = cidx >> 2, kc = cidx & 3;
                *(uint4*)&Bs[h][n][kc * 8] =
                    *(const uint4*)(wcat + (size_t)n * 512 + kt * 32 + kc * 8);
            }
        }
        __syncthreads();
#pragma unroll
        for (int h = 0; h < 2; h++) {
            int kt = kt2 * 2 + h;
            uint4 cur0 = a0, cur1 = a1;
            if (kt < 15) {
                int kg = (kt + 1) * 32;
                const u16* An = (kg < 256) ? (mean1b + kg) : (h1b + (kg - 256));
                a0 = *(const uint4*)(An + r0);
                a1 = *(const uint4*)(An + r1);
            }
            bf16x8 af0 = __builtin_bit_cast(bf16x8, cur0);
            bf16x8 af1 = __builtin_bit_cast(bf16x8, cur1);
#pragma unroll
            for (int u = 0; u < 16; u++) {
                bf16x8 bf = *(const bf16x8*)&Bs[h][u * 16 + m16][quad * 8];
                acc[0][u] = __builtin_amdgcn_mfma_f32_16x16x32_bf16(af0, bf, acc[0][u], 0, 0, 0);
                acc[1][u] = __builtin_amdgcn_mfma_f32_16x16x32_bf16(af1, bf, acc[1][u], 0, 0, 0);
            }
        }
    }
    float wo[16], bb[16];
#pragma unroll
    for (int u = 0; u < 16; u++) { int col = u * 16 + m16; wo[u] = Wout[col]; bb[u] = b2[col]; }
#pragma unroll
    for (int t = 0; t < 2; t++) {
#pragma unroll
        for (int i = 0; i < 4; i++) {
            float p = 0.f;
#pragma unroll
            for (int u = 0; u < 16; u++)
                p = fmaf(fmaxf(acc[t][u][i] + bb[u], 0.f), wo[u], p);
#pragma unroll
            for (int off = 8; off > 0; off >>= 1) p += __shfl_down(p, off, 16);
            int row = bm * 128 + wave * 32 + t * 16 + quad * 4 + i;
            if (m16 == 0 && row < N_N) atomicAdd(&outsum[batch[row]], p);
        }
    }
}

// ---- output head ----
__global__ __launch_bounds__(256) void k_out(const float* __restrict__ outsum, const float* __restrict__ gcnt,
                                             const float* __restrict__ bout, float* __restrict__ out) {
    int g = blockIdx.x * 256 + threadIdx.x;
    if (g < N_G) out[g] = outsum[g] / fmaxf(gcnt[g], 1.f) + bout[0];
}

extern "C" void kernel_launch(void* const* d_in, const int* in_sizes, int n_in,
                              void* d_out, int out_size, void* d_ws, size_t ws_size,
                              hipStream_t stream) {
    const float* x    = (const float*)d_in[0];
    const float* pos  = (const float*)d_in[1];
    const int*   ei   = (const int*)d_in[2];
    const int*   batch= (const int*)d_in[3];
    const float* W1l  = (const float*)d_in[4];
    const float* b1   = (const float*)d_in[5];
    const float* W1r  = (const float*)d_in[6];
    const float* W2l  = (const float*)d_in[7];
    const float* b2   = (const float*)d_in[8];
    const float* W2r  = (const float*)d_in[9];
    const float* Wout = (const float*)d_in[10];
    const float* bout = (const float*)d_in[11];
    float* out = (float*)d_out;
    float* ws  = (float*)d_ws;

    float* outs  = ws + OFF_OUTS;
    int*   gcur  = (int*)(ws + OFF_GCUR);
    float* gcnt  = ws + OFF_GCNT;
    int*   rowp  = (int*)(ws + OFF_ROWP);
    int*   deg   = (int*)(ws + OFF_DEG);
    u32*   ebuf  = (u32*)(ws + OFF_EBUF);
    int*   csrc  = (int*)(ws + OFF_CSRC);
    u16*   h1b   = (u16*)(ws + OFF_H1B);
    u16*   wcat  = (u16*)(ws + OFF_WCAT);
    u16*   xpb   = (u16*)(ws + OFF_XP);
    u16*   mean1b= (u16*)(ws + OFF_MEAN1B);

    hipMemsetAsync(d_ws, 0, ZERO_BYTES, stream);
    k_prep  <<<PACK_BLKS + WCAT_BLKS + GCNT_BLKS, 256, 0, stream>>>(
        x, pos, batch, W2l, W2r, xpb, gcnt, wcat);
    k_bfill <<<NFB, 256, 0, stream>>>(ei, gcur, ebuf);
    k_sort  <<<NBUK, 256, 0, stream>>>(ebuf, gcur, csrc, deg, rowp);
    k_layer1<<<N_N / 16, 256, 0, stream>>>(xpb, rowp, deg, csrc, W1l, b1, W1r, h1b);
    k_agg   <<<N_N / 4, 256, 0, stream>>>(h1b, rowp, deg, csrc, mean1b);
    k_layer2<<<(N_N + 127) / 128, 256, 0, stream>>>(mean1b, h1b, wcat, b2, batch, Wout, outs);
    k_out   <<<(N_G + 255) / 256, 256, 0, stream>>>(outs, gcnt, bout, out);
}

// Round 14
// 395.127 us; speedup vs baseline: 1.2775x; 1.0564x over previous
//
#include <hip/hip_runtime.h>

#define N_N 100000
#define N_E 1600000
#define N_G 5000
#define HID 256
#define IND 14

#define NBUK 391      // buckets: dst>>8, 256 nodes each (391*256 = 100096)
#define CAP 5120      // static per-bucket capacity (E[cnt]=4096, sigma~64; +16 sigma)
#define CH3 8192      // edges per binning block (512 threads)
#define NFB 196       // ceil(N_E/CH3)

typedef __bf16 bf16x8 __attribute__((ext_vector_type(8)));
typedef float f32x4 __attribute__((ext_vector_type(4)));
typedef unsigned short u16;
typedef unsigned int u32;

// ---- workspace layout (units of 4 bytes) ----
constexpr size_t OFF_OUTS  = 0;          // float[5120]   (zeroed)
constexpr size_t OFF_GCUR  = 5120;       // int[391*16]   (zeroed, 64B-padded cursors)
constexpr size_t ZERO_END  = 11520;
constexpr size_t ZERO_BYTES = ZERO_END * 4;
constexpr size_t OFF_GCNT  = 11520;      // float[5120] (fully written)
constexpr size_t OFF_ROWP  = 16640;      // int[100096]
constexpr size_t OFF_DEG   = 116736;     // int[100096]
constexpr size_t OFF_EBUF  = 216832;     // u32[391*5120]
constexpr size_t OFF_CSRC  = 2218752;    // int[391*5120]
constexpr size_t OFF_H1B   = 4220672;    // bf16[100096*256] -> ends 17032960
constexpr size_t OFF_WCAT  = 17032960;   // bf16[256*512]    -> ends 17098496
constexpr size_t OFF_XP    = 17098496;   // bf16[N*16]       -> ends 17898496
constexpr size_t OFF_MEAN1B= 17898496;   // bf16[100096*256] -> ends 30710784
// end = 30710784 floats ~= 123 MB

__device__ __forceinline__ u32 f2b(float f) {
    u32 u = __float_as_uint(f);
    u32 r = u + 0x7FFFu + ((u >> 16) & 1u);
    return r >> 16;
}

#define ADD8(acc, v) do { \
    acc[0] += __uint_as_float(v.x << 16); \
    acc[1] += __uint_as_float(v.x & 0xFFFF0000u); \
    acc[2] += __uint_as_float(v.y << 16); \
    acc[3] += __uint_as_float(v.y & 0xFFFF0000u); \
    acc[4] += __uint_as_float(v.z << 16); \
    acc[5] += __uint_as_float(v.z & 0xFFFF0000u); \
    acc[6] += __uint_as_float(v.w << 16); \
    acc[7] += __uint_as_float(v.w & 0xFFFF0000u); \
} while (0)

// ---- prep: pack xp bf16 + wcat + gcnt (binary search) ----
#define PACK_N (N_N * 16)
#define PACK_BLKS (PACK_N / 256)         // 6250
#define WCAT_BLKS 512
#define GCNT_BLKS 20
__global__ __launch_bounds__(256) void k_prep(const float* __restrict__ x, const float* __restrict__ pos,
                                              const int* __restrict__ batch,
                                              const float* __restrict__ W2l, const float* __restrict__ W2r,
                                              u16* __restrict__ xpb, float* __restrict__ gcnt,
                                              u16* __restrict__ wcat) {
    int tid = threadIdx.x;
    int blk = blockIdx.x;
    if (blk < PACK_BLKS) {
        int idx = blk * 256 + tid;
        int n = idx >> 4, f = idx & 15;
        float v = 0.f;
        if (f < 11) v = x[n * 11 + f];
        else if (f < 14) v = pos[n * 3 + (f - 11)];
        xpb[idx] = (u16)f2b(v);
    } else if (blk < PACK_BLKS + WCAT_BLKS) {
        int i2 = (blk - PACK_BLKS) * 256 + tid;
        int n = i2 >> 9, k = i2 & 511;
        float v = (k < 256) ? W2l[k * HID + n] : W2r[(k - 256) * HID + n];
        wcat[(size_t)n * 512 + k] = (u16)f2b(v);
    } else {
        int g = (blk - PACK_BLKS - WCAT_BLKS) * 256 + tid;
        if (g < N_G) {
            int lo = 0, hi = N_N;
            while (lo < hi) { int mid = (lo + hi) >> 1; if (batch[mid] < g) lo = mid + 1; else hi = mid; }
            int lo2 = lo, hi2 = N_N;
            while (lo2 < hi2) { int mid = (lo2 + hi2) >> 1; if (batch[mid] < g + 1) lo2 = mid + 1; else hi2 = mid; }
            gcnt[g] = (float)(lo2 - lo);
        }
    }
}

// ---- LDS-staged binning: histogram -> LDS scan -> LDS scatter (bucket-ordered) ->
// per-bucket global range reservation -> COALESCED copy-out. Fixes the 64-lines-per-
// store scatter of the naive binning (R4 k_fill signature: ~100 MB WRITE_SIZE). ----
__global__ __launch_bounds__(512) void k_bfill(const int* __restrict__ ei, int* __restrict__ gcur,
                                               u32* __restrict__ ebuf) {
    __shared__ int hist[NBUK];
    __shared__ int lcur[NBUK];
    __shared__ int gbase[NBUK];
    __shared__ int sc[512];
    __shared__ u32 stage[CH3];
    __shared__ u16 bstage[CH3];
    int t = threadIdx.x;
    int base = blockIdx.x * CH3;
    for (int i = t; i < NBUK; i += 512) hist[i] = 0;
    __syncthreads();
#pragma unroll
    for (int i = 0; i < 16; i++) {
        int e = base + i * 512 + t;
        if (e < N_E) atomicAdd(&hist[ei[N_E + e] >> 8], 1);
    }
    __syncthreads();
    sc[t] = (t < NBUK) ? hist[t] : 0;
    __syncthreads();
    for (int off = 1; off < 512; off <<= 1) {
        int v = (t >= off) ? sc[t - off] : 0;
        __syncthreads();
        sc[t] += v;
        __syncthreads();
    }
    if (t < NBUK) lcur[t] = sc[t] - hist[t];   // exclusive base within stage
    __syncthreads();
#pragma unroll
    for (int i = 0; i < 16; i++) {
        int e = base + i * 512 + t;
        if (e < N_E) {
            int d = ei[N_E + e];
            int s = ei[e];
            int b = d >> 8;
            int p = atomicAdd(&lcur[b], 1);
            stage[p] = (u32)s | ((u32)(d & 255) << 17);
            bstage[p] = (u16)b;
        }
    }
    __syncthreads();
    if (t < NBUK) {
        int c = hist[t];
        int o = c ? atomicAdd(&gcur[t * 16], c) : 0;
        gbase[t] = t * CAP + o - (sc[t] - hist[t]);   // so global = gbase[b] + p
    }
    int blockcnt = sc[511];
    __syncthreads();
#pragma unroll
    for (int i = 0; i < 16; i++) {
        int p = i * 512 + t;
        if (p < blockcnt) {
            int b = bstage[p];
            ebuf[gbase[b] + p] = stage[p];
        }
    }
}

// ---- per-bucket counting sort -> csrc, deg, rowp (static bases, no prefix work) ----
__global__ __launch_bounds__(256) void k_sort(const u32* __restrict__ ebuf, const int* __restrict__ gcur,
                                              int* __restrict__ csrc, int* __restrict__ deg,
                                              int* __restrict__ rowp) {
    __shared__ int degL[256];
    __shared__ int sc[256];
    __shared__ int curL[256];
    int t = threadIdx.x;
    int b = blockIdx.x;
    int bs = b * CAP;
    int be = bs + gcur[b * 16];
    degL[t] = 0;
    __syncthreads();
    for (int e = bs + t; e < be; e += 256)
        atomicAdd(&degL[ebuf[e] >> 17], 1);
    __syncthreads();
    int myDeg = degL[t];
    sc[t] = myDeg;
    __syncthreads();
    for (int off = 1; off < 256; off <<= 1) {
        int v = (t >= off) ? sc[t - off] : 0;
        __syncthreads();
        sc[t] += v;
        __syncthreads();
    }
    int excl = sc[t] - myDeg;
    int node = (b << 8) + t;       // < 100096; deg=0 for node >= N_N
    deg[node] = myDeg;
    rowp[node] = bs + excl;
    curL[t] = bs + excl;
    __syncthreads();
    for (int e = bs + t; e < be; e += 256) {
        u32 w = ebuf[e];
        int p = atomicAdd(&curL[w >> 17], 1);
        csrc[p] = (int)(w & 0x1FFFFu);
    }
}

// ---- layer 1: wave-parallel CSR mean-agg on bf16 xp + dual matmul + relu -> bf16 ----
__global__ __launch_bounds__(256) void k_layer1(const u16* __restrict__ xpb,
                                                const int* __restrict__ rowp, const int* __restrict__ deg,
                                                const int* __restrict__ csrc,
                                                const float* __restrict__ W1l, const float* __restrict__ b1,
                                                const float* __restrict__ W1r, u16* __restrict__ h1b) {
    __shared__ float ms[16][16];
    __shared__ float hs[16][16];
    int tid = threadIdx.x;
    int wave = tid >> 6, lane = tid & 63;
    int eg = lane >> 1, c = lane & 1;
#pragma unroll
    for (int nn = 0; nn < 4; nn++) {
        int s = wave * 4 + nn;
        int node = blockIdx.x * 16 + s;
        int st = rowp[node], dg = deg[node];
        float a[8] = {};
        for (int e = st + eg; e < st + dg; e += 32) {
            int nb = csrc[e];
            uint4 v = *(const uint4*)(xpb + (size_t)nb * 16 + c * 8);
            ADD8(a, v);
        }
#pragma unroll
        for (int off = 32; off >= 2; off >>= 1) {
#pragma unroll
            for (int j = 0; j < 8; j++) a[j] += __shfl_down(a[j], off);
        }
        if (lane < 2) {
            float inv = 1.f / (float)max(dg, 1);
#pragma unroll
            for (int j = 0; j < 8; j++) ms[s][c * 8 + j] = a[j] * inv;
        } else if (lane < 4) {
            int cc = lane - 2;
            uint4 v = *(const uint4*)(xpb + (size_t)node * 16 + cc * 8);
            float h[8] = {};
            ADD8(h, v);
#pragma unroll
            for (int j = 0; j < 8; j++) hs[s][cc * 8 + j] = h[j];
        }
    }
    __syncthreads();
    int j = tid;
    float bj = b1[j];
    float acc[16];
#pragma unroll
    for (int ss = 0; ss < 16; ss++) acc[ss] = bj;
#pragma unroll
    for (int k = 0; k < IND; k++) {
        float wl = W1l[k * HID + j];
        float wr = W1r[k * HID + j];
#pragma unroll
        for (int ss = 0; ss < 16; ss++)
            acc[ss] = fmaf(ms[ss][k], wl, fmaf(hs[ss][k], wr, acc[ss]));
    }
    int base = blockIdx.x * 16;
#pragma unroll
    for (int ss = 0; ss < 16; ss++)
        h1b[(size_t)(base + ss) * HID + j] = (u16)f2b(fmaxf(acc[ss], 0.f));
}

// ---- layer-2 mean aggregation: 1 wave/node, 4 rows in flight; split into two
// half-grid launches for top-5 visibility (wall: ~3.9 TB/s scattered-gather) ----
__global__ __launch_bounds__(256) void k_agg(const u16* __restrict__ h1b, const int* __restrict__ rowp,
                                             const int* __restrict__ deg, const int* __restrict__ csrc,
                                             u16* __restrict__ mean1b, int nodeBase) {
    int tid = threadIdx.x;
    int node = nodeBase + blockIdx.x * 4 + (tid >> 6);
    int lane = tid & 63;
    int half = lane >> 5, l32 = lane & 31;
    int st = rowp[node], dg = deg[node];
    int end = st + dg;
    const size_t roff = (size_t)l32 * 8;
    float accA[8] = {}, accB[8] = {};
    int e = st + half;
    for (; e + 2 < end; e += 4) {
        int nb1 = csrc[e];
        int nb2 = csrc[e + 2];
        uint4 v1 = *(const uint4*)(h1b + (size_t)nb1 * HID + roff);
        uint4 v2 = *(const uint4*)(h1b + (size_t)nb2 * HID + roff);
        ADD8(accA, v1);
        ADD8(accB, v2);
    }
    if (e < end) {
        int nb = csrc[e];
        uint4 v = *(const uint4*)(h1b + (size_t)nb * HID + roff);
        ADD8(accA, v);
    }
    float acc[8];
#pragma unroll
    for (int j = 0; j < 8; j++) acc[j] = accA[j] + accB[j];
#pragma unroll
    for (int j = 0; j < 8; j++) acc[j] += __shfl_down(acc[j], 32);
    if (lane < 32) {
        float inv = 1.f / (float)max(dg, 1);
        uint4 o;
        o.x = f2b(acc[0] * inv) | (f2b(acc[1] * inv) << 16);
        o.y = f2b(acc[2] * inv) | (f2b(acc[3] * inv) << 16);
        o.z = f2b(acc[4] * inv) | (f2b(acc[5] * inv) << 16);
        o.w = f2b(acc[6] * inv) | (f2b(acc[7] * inv) << 16);
        *(uint4*)(mean1b + (size_t)node * HID + roff) = o;
    }
}

// ---- layer 2 (BM=128, Bs double-kt — ~24 us): direct-global A-frags + register
// prefetch; fused relu + Wout-dot + pool atomic ----
__global__ __launch_bounds__(256, 2) void k_layer2(const u16* __restrict__ mean1b, const u16* __restrict__ h1b,
                                                   const u16* __restrict__ wcat, const float* __restrict__ b2,
                                                   const int* __restrict__ batch, const float* __restrict__ Wout,
                                                   float* __restrict__ outsum) {
    __shared__ u16 Bs[2][256][40];
    int tid = threadIdx.x;
    int wave = tid >> 6, lane = tid & 63;
    int quad = lane >> 4, m16 = lane & 15;
    int bm = blockIdx.x;
    const size_t r0 = (size_t)(bm * 128 + wave * 32 + m16) * HID + quad * 8;
    const size_t r1 = r0 + 16 * HID;
    f32x4 acc[2][16] = {};
    uint4 a0 = *(const uint4*)(mean1b + r0);
    uint4 a1 = *(const uint4*)(mean1b + r1);
    for (int kt2 = 0; kt2 < 8; kt2++) {
        __syncthreads();
#pragma unroll
        for (int h = 0; h < 2; h++) {
            int kt = kt2 * 2 + h;
#pragma unroll
            for (int i = 0; i < 4; i++) {
                int cidx = tid + 256 * i;
                int n = cidx >> 2, kc = cidx & 3;
                *(uint4*)&Bs[h][n][kc * 8] =
                    *(const uint4*)(wcat + (size_t)n * 512 + kt * 32 + kc * 8);
            }
        }
        __syncthreads();
#pragma unroll
        for (int h = 0; h < 2; h++) {
            int kt = kt2 * 2 + h;
            uint4 cur0 = a0, cur1 = a1;
            if (kt < 15) {
                int kg = (kt + 1) * 32;
                const u16* An = (kg < 256) ? (mean1b + kg) : (h1b + (kg - 256));
                a0 = *(const uint4*)(An + r0);
                a1 = *(const uint4*)(An + r1);
            }
            bf16x8 af0 = __builtin_bit_cast(bf16x8, cur0);
            bf16x8 af1 = __builtin_bit_cast(bf16x8, cur1);
#pragma unroll
            for (int u = 0; u < 16; u++) {
                bf16x8 bf = *(const bf16x8*)&Bs[h][u * 16 + m16][quad * 8];
                acc[0][u] = __builtin_amdgcn_mfma_f32_16x16x32_bf16(af0, bf, acc[0][u], 0, 0, 0);
                acc[1][u] = __builtin_amdgcn_mfma_f32_16x16x32_bf16(af1, bf, acc[1][u], 0, 0, 0);
            }
        }
    }
    float wo[16], bb[16];
#pragma unroll
    for (int u = 0; u < 16; u++) { int col = u * 16 + m16; wo[u] = Wout[col]; bb[u] = b2[col]; }
#pragma unroll
    for (int t = 0; t < 2; t++) {
#pragma unroll
        for (int i = 0; i < 4; i++) {
            float p = 0.f;
#pragma unroll
            for (int u = 0; u < 16; u++)
                p = fmaf(fmaxf(acc[t][u][i] + bb[u], 0.f), wo[u], p);
#pragma unroll
            for (int off = 8; off > 0; off >>= 1) p += __shfl_down(p, off, 16);
            int row = bm * 128 + wave * 32 + t * 16 + quad * 4 + i;
            if (m16 == 0 && row < N_N) atomicAdd(&outsum[batch[row]], p);
        }
    }
}

// ---- output head ----
__global__ __launch_bounds__(256) void k_out(const float* __restrict__ outsum, const float* __restrict__ gcnt,
                                             const float* __restrict__ bout, float* __restrict__ out) {
    int g = blockIdx.x * 256 + threadIdx.x;
    if (g < N_G) out[g] = outsum[g] / fmaxf(gcnt[g], 1.f) + bout[0];
}

extern "C" void kernel_launch(void* const* d_in, const int* in_sizes, int n_in,
                              void* d_out, int out_size, void* d_ws, size_t ws_size,
                              hipStream_t stream) {
    const float* x    = (const float*)d_in[0];
    const float* pos  = (const float*)d_in[1];
    const int*   ei   = (const int*)d_in[2];
    const int*   batch= (const int*)d_in[3];
    const float* W1l  = (const float*)d_in[4];
    const float* b1   = (const float*)d_in[5];
    const float* W1r  = (const float*)d_in[6];
    const float* W2l  = (const float*)d_in[7];
    const float* b2   = (const float*)d_in[8];
    const float* W2r  = (const float*)d_in[9];
    const float* Wout = (const float*)d_in[10];
    const float* bout = (const float*)d_in[11];
    float* out = (float*)d_out;
    float* ws  = (float*)d_ws;

    float* outs  = ws + OFF_OUTS;
    int*   gcur  = (int*)(ws + OFF_GCUR);
    float* gcnt  = ws + OFF_GCNT;
    int*   rowp  = (int*)(ws + OFF_ROWP);
    int*   deg   = (int*)(ws + OFF_DEG);
    u32*   ebuf  = (u32*)(ws + OFF_EBUF);
    int*   csrc  = (int*)(ws + OFF_CSRC);
    u16*   h1b   = (u16*)(ws + OFF_H1B);
    u16*   wcat  = (u16*)(ws + OFF_WCAT);
    u16*   xpb   = (u16*)(ws + OFF_XP);
    u16*   mean1b= (u16*)(ws + OFF_MEAN1B);

    hipMemsetAsync(d_ws, 0, ZERO_BYTES, stream);
    k_prep  <<<PACK_BLKS + WCAT_BLKS + GCNT_BLKS, 256, 0, stream>>>(
        x, pos, batch, W2l, W2r, xpb, gcnt, wcat);
    k_bfill <<<NFB, 512, 0, stream>>>(ei, gcur, ebuf);
    k_sort  <<<NBUK, 256, 0, stream>>>(ebuf, gcur, csrc, deg, rowp);
    k_layer1<<<N_N / 16, 256, 0, stream>>>(xpb, rowp, deg, csrc, W1l, b1, W1r, h1b);
    k_agg   <<<N_N / 8, 256, 0, stream>>>(h1b, rowp, deg, csrc, mean1b, 0);
    k_agg   <<<N_N / 8, 256, 0, stream>>>(h1b, rowp, deg, csrc, mean1b, N_N / 2);
    k_layer2<<<(N_N + 127) / 128, 256, 0, stream>>>(mean1b, h1b, wcat, b2, batch, Wout, outs);
    k_out   <<<(N_G + 255) / 256, 256, 0, stream>>>(outs, gcnt, bout, out);
}